// Round 4
// baseline (1245.316 us; speedup 1.0000x reference)
//
#include <hip/hip_runtime.h>
#include <math.h>

// Markowitz min-variance via FISTA, one block (512 thr, 8 waves) per problem.
// Q register-resident: thread (lane=tid&63, e=tid>>6) owns Q[4*lane..+3][32*e..+31].
// R4: ALL waves redundantly reduce + project (bit-identical, uniform control
// flow) -> no wave0 serial section; double-buffered p_lds -> ONE barrier/iter;
// y published to per-wave private slice (own-wave read, no barrier).

#define NA    256
#define CAPW  0.05f

typedef float v2f __attribute__((ext_vector_type(2)));

// ---- DPP wave-64 reductions ----
template<int CTRL, int RM>
__device__ __forceinline__ float dpp0(float x) {      // old = 0, bound_ctrl = true
    return __int_as_float(__builtin_amdgcn_update_dpp(
        0, __float_as_int(x), CTRL, RM, 0xf, true));
}
template<int CTRL, int RM>
__device__ __forceinline__ float dppI(float x, float ident) { // old = ident
    return __int_as_float(__builtin_amdgcn_update_dpp(
        __float_as_int(ident), __float_as_int(x), CTRL, RM, 0xf, false));
}
__device__ __forceinline__ float bcast63(float x) {
    return __int_as_float(__builtin_amdgcn_readlane(__float_as_int(x), 63));
}
__device__ __forceinline__ float wsum(float x) {
    x += dpp0<0x111, 0xf>(x);   // row_shr:1
    x += dpp0<0x112, 0xf>(x);   // row_shr:2
    x += dpp0<0x114, 0xf>(x);   // row_shr:4
    x += dpp0<0x118, 0xf>(x);   // row_shr:8
    x += dpp0<0x142, 0xa>(x);   // row_bcast:15 -> rows 1,3
    x += dpp0<0x143, 0xc>(x);   // row_bcast:31 -> rows 2,3
    return bcast63(x);
}
__device__ __forceinline__ float wmin(float x) {
    const float I = 1e30f;
    x = fminf(x, dppI<0x111, 0xf>(x, I));
    x = fminf(x, dppI<0x112, 0xf>(x, I));
    x = fminf(x, dppI<0x114, 0xf>(x, I));
    x = fminf(x, dppI<0x118, 0xf>(x, I));
    x = fminf(x, dppI<0x142, 0xa>(x, I));
    x = fminf(x, dppI<0x143, 0xc>(x, I));
    return bcast63(x);
}
__device__ __forceinline__ float wmax(float x) {
    const float I = -1e30f;
    x = fmaxf(x, dppI<0x111, 0xf>(x, I));
    x = fmaxf(x, dppI<0x112, 0xf>(x, I));
    x = fmaxf(x, dppI<0x114, 0xf>(x, I));
    x = fmaxf(x, dppI<0x118, 0xf>(x, I));
    x = fmaxf(x, dppI<0x142, 0xa>(x, I));
    x = fmaxf(x, dppI<0x143, 0xc>(x, I));
    return bcast63(x);
}

__global__ void __launch_bounds__(512, 2)
markowitz_fista(const float* __restrict__ A, float* __restrict__ out)
{
    __shared__ float A_lds[32 * 256];      // build-phase staging (32 KB)
    __shared__ float p_lds[2][8 * 256];    // double-buffered matvec partials
    __shared__ float y_sl[8 * 32];         // per-wave private y slice

    const int tid  = threadIdx.x;
    const int b    = blockIdx.x;
    const int lane = tid & 63;
    const int e    = tid >> 6;             // wave id == col-chunk
    const int R0   = lane * 4;
    const int C0   = e * 32;

    const float* __restrict__ Ab = A + (size_t)b * NA * NA;

    // ---------------- Phase 1: Q = A^T A into registers (packed fp32) -------
    v2f q2[4][16];
    #pragma unroll
    for (int a = 0; a < 4; ++a)
        #pragma unroll
        for (int k = 0; k < 16; ++k) q2[a][k] = (v2f){0.0f, 0.0f};

    for (int it = 0; it < 8; ++it) {
        __syncthreads();
        const float4* src = (const float4*)(Ab + it * 32 * 256);
        float4* dst = (float4*)A_lds;
        #pragma unroll
        for (int qd = 0; qd < 4; ++qd) dst[qd * 512 + tid] = src[qd * 512 + tid];
        __syncthreads();
        for (int ii = 0; ii < 32; ++ii) {
            const float* row = A_lds + ii * 256;
            float4 rv = *(const float4*)(row + R0);
            v2f r0 = {rv.x, rv.x}, r1 = {rv.y, rv.y}, r2 = {rv.z, rv.z}, r3 = {rv.w, rv.w};
            #pragma unroll
            for (int cc = 0; cc < 8; ++cc) {
                float4 cv = *(const float4*)(row + C0 + 4 * cc);
                v2f clo = {cv.x, cv.y}, chi = {cv.z, cv.w};
                q2[0][2*cc  ] = __builtin_elementwise_fma(r0, clo, q2[0][2*cc  ]);
                q2[0][2*cc+1] = __builtin_elementwise_fma(r0, chi, q2[0][2*cc+1]);
                q2[1][2*cc  ] = __builtin_elementwise_fma(r1, clo, q2[1][2*cc  ]);
                q2[1][2*cc+1] = __builtin_elementwise_fma(r1, chi, q2[1][2*cc+1]);
                q2[2][2*cc  ] = __builtin_elementwise_fma(r2, clo, q2[2][2*cc  ]);
                q2[2][2*cc+1] = __builtin_elementwise_fma(r2, chi, q2[2][2*cc+1]);
                q2[3][2*cc  ] = __builtin_elementwise_fma(r3, clo, q2[3][2*cc  ]);
                q2[3][2*cc+1] = __builtin_elementwise_fma(r3, chi, q2[3][2*cc+1]);
            }
        }
    }

    // publish this lane's 4 y-values into the owning wave's private slice.
    // wave e consumes y[32e..32e+31], produced by its own lanes 8e..8e+7:
    // same-wave DS ordering -> no barrier needed.
    auto publish_y = [&](float y0v, float y1v, float y2v, float y3v) {
        if ((lane >> 3) == e)
            *(float4*)(y_sl + C0 + ((lane & 7) << 2)) = make_float4(y0v, y1v, y2v, y3v);
    };

    // partials of Q*y into p_lds[buf]; single barrier at the end.
    auto partials = [&](int buf) {
        v2f aL0 = {0,0}, aL1 = {0,0}, aL2 = {0,0}, aL3 = {0,0};
        v2f aH0 = {0,0}, aH1 = {0,0}, aH2 = {0,0}, aH3 = {0,0};
        const float* yv = y_sl + C0;
        #pragma unroll
        for (int cc = 0; cc < 8; ++cc) {
            float4 y4 = *(const float4*)(yv + 4 * cc);
            v2f ylo = {y4.x, y4.y}, yhi = {y4.z, y4.w};
            aL0 = __builtin_elementwise_fma(q2[0][2*cc  ], ylo, aL0);
            aH0 = __builtin_elementwise_fma(q2[0][2*cc+1], yhi, aH0);
            aL1 = __builtin_elementwise_fma(q2[1][2*cc  ], ylo, aL1);
            aH1 = __builtin_elementwise_fma(q2[1][2*cc+1], yhi, aH1);
            aL2 = __builtin_elementwise_fma(q2[2][2*cc  ], ylo, aL2);
            aH2 = __builtin_elementwise_fma(q2[2][2*cc+1], yhi, aH2);
            aL3 = __builtin_elementwise_fma(q2[3][2*cc  ], ylo, aL3);
            aH3 = __builtin_elementwise_fma(q2[3][2*cc+1], yhi, aH3);
        }
        v2f s0 = aL0 + aH0, s1 = aL1 + aH1, s2 = aL2 + aH2, s3 = aL3 + aH3;
        *(float4*)(&p_lds[buf][e * 256 + R0]) =
            make_float4(s0.x + s0.y, s1.x + s1.y, s2.x + s2.y, s3.x + s3.y);
        __syncthreads();
    };
    // every wave redundantly reduces the 8 partials for rows 4*lane..+3
    auto reduceg = [&](int buf) -> float4 {
        float4 r = *(const float4*)(&p_lds[buf][R0]);
        #pragma unroll
        for (int ee = 1; ee < 8; ++ee) {
            float4 pv = *(const float4*)(&p_lds[buf][ee * 256 + R0]);
            r.x += pv.x; r.y += pv.y; r.z += pv.z; r.w += pv.w;
        }
        return r;
    };

    // ---------------- Phase 2: power iteration (all waves redundant) --------
    float u0 = 0.0625f, u1 = 0.0625f, u2 = 0.0625f, u3 = 0.0625f;
    publish_y(u0, u1, u2, u3);
    int pb = 0;
    for (int p = 0; p < 30; ++p) {
        partials(pb);
        float4 g4 = reduceg(pb); pb ^= 1;
        float ss = wsum(g4.x*g4.x + g4.y*g4.y + g4.z*g4.z + g4.w*g4.w);
        float inv = 1.0f / (sqrtf(ss) + 1e-12f);
        u0 = g4.x * inv; u1 = g4.y * inv; u2 = g4.z * inv; u3 = g4.w * inv;
        publish_y(u0, u1, u2, u3);
    }
    partials(pb);
    {   // Rayleigh quotient + step
        float4 g4 = reduceg(pb); pb ^= 1;
        float lm = wsum(u0*g4.x + u1*g4.y + u2*g4.z + u3*g4.w);
        float step = 1.0f / (2.0f * lm + 1e-12f);
        u0 = 2.0f * step;                     // reuse u0 as step2
    }
    const float step2 = u0;

    float t = 1.0f, tau_ws = 0.0f, rm = 0.0f;
    float wa = 1.0f/256.0f, wb = wa, wc = wa, wd = wa;   // project(uniform)=uniform
    float ya = wa, yb = wa, yc = wa, yd = wa;
    publish_y(ya, yb, yc, yd);

    // ---------------- Phase 3: FISTA (all waves redundant, 1 barrier/iter) --
    for (int itn = 0; itn < 300; ++itn) {
        partials(pb);
        float4 g4 = reduceg(pb); pb ^= 1;
        float v0 = ya - step2 * g4.x;
        float v1 = yb - step2 * g4.y;
        float v2 = yc - step2 * g4.z;
        float v3 = yd - step2 * g4.w;

        float lo = wmin(fminf(fminf(v0, v1), fminf(v2, v3))) - CAPW;
        float hi = wmax(fmaxf(fmaxf(v0, v1), fmaxf(v2, v3))) + CAPW;
        float tau = fminf(fmaxf(tau_ws, lo), hi);

        float s = 0.f, cnt = 1.f, sm1 = 0.f;
        bool have = false;
        for (int ni = 0; ni < 10; ++ni) {
            float z0 = v0 - tau, z1 = v1 - tau, z2 = v2 - tau, z3 = v3 - tau;
            float c0 = fminf(fmaxf(z0, -CAPW), CAPW);
            float c1 = fminf(fmaxf(z1, -CAPW), CAPW);
            float c2 = fminf(fmaxf(z2, -CAPW), CAPW);
            float c3 = fminf(fmaxf(z3, -CAPW), CAPW);
            s   = wsum(c0 + c1 + c2 + c3);
            cnt = wsum((fabsf(z0) < CAPW ? 1.f : 0.f) +
                       (fabsf(z1) < CAPW ? 1.f : 0.f) +
                       (fabsf(z2) < CAPW ? 1.f : 0.f) +
                       (fabsf(z3) < CAPW ? 1.f : 0.f));
            sm1 = s - 1.0f;
            if (fabsf(sm1) <= 1e-5f) { have = true; break; }   // wave-uniform
            if (sm1 > 0.0f) lo = tau; else hi = tau;
            float tn2 = tau + sm1 / fmaxf(cnt, 1.0f);   // Newton: s' = -n_int
            if (!(tn2 > lo && tn2 < hi)) tn2 = 0.5f * (lo + hi);
            tau = tn2;
        }
        if (!have) {   // bound-exit: re-eval (s,cnt) at final tau
            float z0 = v0 - tau, z1 = v1 - tau, z2 = v2 - tau, z3 = v3 - tau;
            float c0 = fminf(fmaxf(z0, -CAPW), CAPW);
            float c1 = fminf(fmaxf(z1, -CAPW), CAPW);
            float c2 = fminf(fmaxf(z2, -CAPW), CAPW);
            float c3 = fminf(fmaxf(z3, -CAPW), CAPW);
            s   = wsum(c0 + c1 + c2 + c3);
            cnt = wsum((fabsf(z0) < CAPW ? 1.f : 0.f) +
                       (fabsf(z1) < CAPW ? 1.f : 0.f) +
                       (fabsf(z2) < CAPW ? 1.f : 0.f) +
                       (fabsf(z3) < CAPW ? 1.f : 0.f));
            sm1 = s - 1.0f;
        }
        // exact active-set tau == one Newton step from converged point
        float tauf = tau + sm1 / fmaxf(cnt, 1.0f);
        tau_ws = tauf;
        float w0n = fminf(fmaxf(v0 - tauf, -CAPW), CAPW);
        float w1n = fminf(fmaxf(v1 - tauf, -CAPW), CAPW);
        float w2n = fminf(fmaxf(v2 - tauf, -CAPW), CAPW);
        float w3n = fminf(fmaxf(v3 - tauf, -CAPW), CAPW);

        float tn = 0.5f * (1.0f + sqrtf(1.0f + 4.0f * t * t));
        float beta = (t - 1.0f) / tn;
        float y0n = w0n + beta * (w0n - wa);
        float y1n = w1n + beta * (w1n - wb);
        float y2n = w2n + beta * (w2n - wc);
        float y3n = w3n + beta * (w3n - wd);

        float dm = fmaxf(fmaxf(fabsf(w0n - wa), fabsf(w1n - wb)),
                         fmaxf(fabsf(w2n - wc), fabsf(w3n - wd)));
        rm = fmaxf(rm, dm);

        wa = w0n; wb = w1n; wc = w2n; wd = w3n;
        ya = y0n; yb = y1n; yc = y2n; yd = y3n;
        t = tn;
        publish_y(ya, yb, yc, yd);

        // frozen-w early exit: identical in every wave -> uniform break
        if ((itn & 7) == 7) {
            float rmax = wmax(rm);
            rm = 0.0f;
            if (rmax < 1e-10f) break;
        }
    }

    if (tid < 64) {
        *(float4*)(out + b * 256 + R0) = make_float4(wa, wb, wc, wd);
    }
}

extern "C" void kernel_launch(void* const* d_in, const int* in_sizes, int n_in,
                              void* d_out, int out_size, void* d_ws, size_t ws_size,
                              hipStream_t stream) {
    (void)in_sizes; (void)n_in; (void)d_ws; (void)ws_size; (void)out_size;
    const float* A = (const float*)d_in[0];
    float* out = (float*)d_out;
    hipLaunchKernelGGL(markowitz_fista, dim3(512), dim3(512), 0, stream, A, out);
}

// Round 5
// 1071.818 us; speedup vs baseline: 1.1619x; 1.1619x over previous
//
#include <hip/hip_runtime.h>
#include <math.h>

// Markowitz min-variance via FISTA, one block (512 thr, 8 waves) per problem.
// Thread (lane=tid&63, e=tid>>6) owns Q[4*lane..+3][32*e..+31] in REGISTERS.
// R5: de-spill Q -- R1..R4 reported VGPR_Count~100 (< the 128 Q needs), i.e.
// the whole Q tile lived in scratch and every matvec re-read 256 KB/block
// (~4600 cyc, the measured iter wall). Q is now 64 NAMED v2f locals via
// X-macros (no array, no lambdas -> guaranteed SSA/VGPR). Structure = R3
// (fastest measured): wave0-only projection, 2 barriers/iter.

#define NA    256
#define CAPW  0.05f

typedef float v2f __attribute__((ext_vector_type(2)));

// ---- DPP wave-64 reductions ----
template<int CTRL, int RM>
__device__ __forceinline__ float dpp0(float x) {      // old = 0, bound_ctrl = true
    return __int_as_float(__builtin_amdgcn_update_dpp(
        0, __float_as_int(x), CTRL, RM, 0xf, true));
}
template<int CTRL, int RM>
__device__ __forceinline__ float dppI(float x, float ident) { // old = ident
    return __int_as_float(__builtin_amdgcn_update_dpp(
        __float_as_int(ident), __float_as_int(x), CTRL, RM, 0xf, false));
}
__device__ __forceinline__ float bcast63(float x) {
    return __int_as_float(__builtin_amdgcn_readlane(__float_as_int(x), 63));
}
__device__ __forceinline__ float wsum(float x) {
    x += dpp0<0x111, 0xf>(x);   // row_shr:1
    x += dpp0<0x112, 0xf>(x);   // row_shr:2
    x += dpp0<0x114, 0xf>(x);   // row_shr:4
    x += dpp0<0x118, 0xf>(x);   // row_shr:8
    x += dpp0<0x142, 0xa>(x);   // row_bcast:15 -> rows 1,3
    x += dpp0<0x143, 0xc>(x);   // row_bcast:31 -> rows 2,3
    return bcast63(x);
}
__device__ __forceinline__ float wmin(float x) {
    const float I = 1e30f;
    x = fminf(x, dppI<0x111, 0xf>(x, I));
    x = fminf(x, dppI<0x112, 0xf>(x, I));
    x = fminf(x, dppI<0x114, 0xf>(x, I));
    x = fminf(x, dppI<0x118, 0xf>(x, I));
    x = fminf(x, dppI<0x142, 0xa>(x, I));
    x = fminf(x, dppI<0x143, 0xc>(x, I));
    return bcast63(x);
}
__device__ __forceinline__ float wmax(float x) {
    const float I = -1e30f;
    x = fmaxf(x, dppI<0x111, 0xf>(x, I));
    x = fmaxf(x, dppI<0x112, 0xf>(x, I));
    x = fmaxf(x, dppI<0x114, 0xf>(x, I));
    x = fmaxf(x, dppI<0x118, 0xf>(x, I));
    x = fmaxf(x, dppI<0x142, 0xa>(x, I));
    x = fmaxf(x, dppI<0x143, 0xc>(x, I));
    return bcast63(x);
}

// ---- X-macros over the 8 column-chunks of the per-thread Q tile ----
#define FOR_CC(M) M(0) M(1) M(2) M(3) M(4) M(5) M(6) M(7)

// declare 64 named v2f accumulators (4 rows x 8 cc x {L,H})
#define QDECL(cc) \
    v2f q0_##cc##L = {0,0}, q0_##cc##H = {0,0}, \
        q1_##cc##L = {0,0}, q1_##cc##H = {0,0}, \
        q2_##cc##L = {0,0}, q2_##cc##H = {0,0}, \
        q3_##cc##L = {0,0}, q3_##cc##H = {0,0};

// build-phase rank-1 update for one LDS row
#define QBUILD(cc) { \
    float4 cv = *(const float4*)(row + C0 + 4*cc); \
    v2f clo = {cv.x, cv.y}, chi = {cv.z, cv.w}; \
    q0_##cc##L = __builtin_elementwise_fma(r0s, clo, q0_##cc##L); \
    q0_##cc##H = __builtin_elementwise_fma(r0s, chi, q0_##cc##H); \
    q1_##cc##L = __builtin_elementwise_fma(r1s, clo, q1_##cc##L); \
    q1_##cc##H = __builtin_elementwise_fma(r1s, chi, q1_##cc##H); \
    q2_##cc##L = __builtin_elementwise_fma(r2s, clo, q2_##cc##L); \
    q2_##cc##H = __builtin_elementwise_fma(r2s, chi, q2_##cc##H); \
    q3_##cc##L = __builtin_elementwise_fma(r3s, clo, q3_##cc##L); \
    q3_##cc##H = __builtin_elementwise_fma(r3s, chi, q3_##cc##H); }

// matvec partial for one column-chunk
#define QMV(cc) { \
    float4 y4 = *(const float4*)(yv + 4*cc); \
    v2f ylo = {y4.x, y4.y}, yhi = {y4.z, y4.w}; \
    aL0 = __builtin_elementwise_fma(q0_##cc##L, ylo, aL0); \
    aH0 = __builtin_elementwise_fma(q0_##cc##H, yhi, aH0); \
    aL1 = __builtin_elementwise_fma(q1_##cc##L, ylo, aL1); \
    aH1 = __builtin_elementwise_fma(q1_##cc##H, yhi, aH1); \
    aL2 = __builtin_elementwise_fma(q2_##cc##L, ylo, aL2); \
    aH2 = __builtin_elementwise_fma(q2_##cc##H, yhi, aH2); \
    aL3 = __builtin_elementwise_fma(q3_##cc##L, ylo, aL3); \
    aH3 = __builtin_elementwise_fma(q3_##cc##H, yhi, aH3); }

// full partials pass: B1, matvec, write p_lds, B2
#define PARTIALS() do { \
    __syncthreads(); \
    v2f aL0={0,0},aH0={0,0},aL1={0,0},aH1={0,0}; \
    v2f aL2={0,0},aH2={0,0},aL3={0,0},aH3={0,0}; \
    const float* yv = y_lds + C0; \
    FOR_CC(QMV) \
    v2f s0 = aL0+aH0, s1 = aL1+aH1, s2 = aL2+aH2, s3 = aL3+aH3; \
    *(float4*)(p_lds + e*256 + R0) = \
        make_float4(s0.x+s0.y, s1.x+s1.y, s2.x+s2.y, s3.x+s3.y); \
    __syncthreads(); \
} while (0)

__global__ void __launch_bounds__(512, 2)
markowitz_fista(const float* __restrict__ A, float* __restrict__ out)
{
    __shared__ float A_lds[32 * 256];   // build-phase staging (32 KB)
    __shared__ float y_lds[256];        // published y / u vector
    __shared__ float p_lds[8 * 256];    // matvec partials, [e][r] layout
    __shared__ int   done_flag;

    const int tid  = threadIdx.x;
    const int b    = blockIdx.x;
    const int lane = tid & 63;
    const int e    = tid >> 6;          // wave id == col-chunk
    const int R0   = lane * 4;
    const int C0   = e * 32;

    const float* __restrict__ Ab = A + (size_t)b * NA * NA;

    // ---------------- Phase 1: Q = A^T A into named registers ----------------
    FOR_CC(QDECL)

    for (int it = 0; it < 8; ++it) {
        __syncthreads();
        const float4* src = (const float4*)(Ab + it * 32 * 256);
        float4* dst = (float4*)A_lds;
        #pragma unroll
        for (int qd = 0; qd < 4; ++qd) dst[qd * 512 + tid] = src[qd * 512 + tid];
        __syncthreads();
        for (int ii = 0; ii < 32; ++ii) {
            const float* row = A_lds + ii * 256;
            float4 rv = *(const float4*)(row + R0);   // own rows: conflict-free
            v2f r0s = {rv.x, rv.x}, r1s = {rv.y, rv.y};
            v2f r2s = {rv.z, rv.z}, r3s = {rv.w, rv.w};
            FOR_CC(QBUILD)                            // col chunk: broadcast reads
        }
    }

    // wave0: reduce the 8 partials for rows 4*lane..+3 (used via macro-free code)
    // ---------------- Phase 2: power iteration for step size ----------------
    if (tid < 64) {
        *(float4*)(y_lds + R0) = make_float4(0.0625f, 0.0625f, 0.0625f, 0.0625f);
    }
    float u0 = 0.f, u1 = 0.f, u2 = 0.f, u3 = 0.f;
    for (int p = 0; p < 30; ++p) {
        PARTIALS();
        if (tid < 64) {
            float4 g4 = *(const float4*)(p_lds + R0);
            #pragma unroll
            for (int ee = 1; ee < 8; ++ee) {
                float4 pv = *(const float4*)(p_lds + ee * 256 + R0);
                g4.x += pv.x; g4.y += pv.y; g4.z += pv.z; g4.w += pv.w;
            }
            float ss = wsum(g4.x*g4.x + g4.y*g4.y + g4.z*g4.z + g4.w*g4.w);
            float inv = 1.0f / (sqrtf(ss) + 1e-12f);
            u0 = g4.x * inv; u1 = g4.y * inv; u2 = g4.z * inv; u3 = g4.w * inv;
            *(float4*)(y_lds + R0) = make_float4(u0, u1, u2, u3);
        }
    }
    PARTIALS();   // Q*u for Rayleigh quotient

    float step2 = 0.f, t = 1.0f, tau_ws = 0.0f, rm = 0.0f;
    float wa = 0.f, wb = 0.f, wc = 0.f, wd = 0.f;
    float ya = 0.f, yb = 0.f, yc = 0.f, yd = 0.f;
    if (tid < 64) {
        float4 g4 = *(const float4*)(p_lds + R0);
        #pragma unroll
        for (int ee = 1; ee < 8; ++ee) {
            float4 pv = *(const float4*)(p_lds + ee * 256 + R0);
            g4.x += pv.x; g4.y += pv.y; g4.z += pv.z; g4.w += pv.w;
        }
        float lm = wsum(u0*g4.x + u1*g4.y + u2*g4.z + u3*g4.w);
        float step = 1.0f / (2.0f * lm + 1e-12f);
        step2 = 2.0f * step;
        wa = wb = wc = wd = 1.0f / 256.0f;   // project(uniform) = uniform (tau=0)
        ya = yb = yc = yd = 1.0f / 256.0f;
        *(float4*)(y_lds + R0) = make_float4(ya, yb, yc, yd);
    }
    if (tid == 0) done_flag = 0;             // ordered by next B1

    // ---------------- Phase 3: FISTA (wave0 projection, 2 barriers/iter) ----
    for (int itn = 0; itn < 300; ++itn) {
        __syncthreads();                      // B1: y_lds / done_flag visible
        if (done_flag) break;                 // block-uniform
        {
            v2f aL0={0,0},aH0={0,0},aL1={0,0},aH1={0,0};
            v2f aL2={0,0},aH2={0,0},aL3={0,0},aH3={0,0};
            const float* yv = y_lds + C0;
            FOR_CC(QMV)
            v2f s0 = aL0+aH0, s1 = aL1+aH1, s2 = aL2+aH2, s3 = aL3+aH3;
            *(float4*)(p_lds + e*256 + R0) =
                make_float4(s0.x+s0.y, s1.x+s1.y, s2.x+s2.y, s3.x+s3.y);
        }
        __syncthreads();                      // B2: p_lds visible

        if (tid < 64) {
            float4 g4 = *(const float4*)(p_lds + R0);
            #pragma unroll
            for (int ee = 1; ee < 8; ++ee) {
                float4 pv = *(const float4*)(p_lds + ee * 256 + R0);
                g4.x += pv.x; g4.y += pv.y; g4.z += pv.z; g4.w += pv.w;
            }
            float v0 = ya - step2 * g4.x;
            float v1 = yb - step2 * g4.y;
            float v2 = yc - step2 * g4.z;
            float v3 = yd - step2 * g4.w;

            float lo = wmin(fminf(fminf(v0, v1), fminf(v2, v3))) - CAPW;
            float hi = wmax(fmaxf(fmaxf(v0, v1), fmaxf(v2, v3))) + CAPW;
            float tau = fminf(fmaxf(tau_ws, lo), hi);

            float s = 0.f, cnt = 1.f, sm1 = 0.f;
            bool have = false;
            for (int ni = 0; ni < 10; ++ni) {
                float z0 = v0 - tau, z1 = v1 - tau, z2 = v2 - tau, z3 = v3 - tau;
                float c0 = fminf(fmaxf(z0, -CAPW), CAPW);
                float c1 = fminf(fmaxf(z1, -CAPW), CAPW);
                float c2 = fminf(fmaxf(z2, -CAPW), CAPW);
                float c3 = fminf(fmaxf(z3, -CAPW), CAPW);
                s   = wsum(c0 + c1 + c2 + c3);
                cnt = wsum((fabsf(z0) < CAPW ? 1.f : 0.f) +
                           (fabsf(z1) < CAPW ? 1.f : 0.f) +
                           (fabsf(z2) < CAPW ? 1.f : 0.f) +
                           (fabsf(z3) < CAPW ? 1.f : 0.f));
                sm1 = s - 1.0f;
                if (fabsf(sm1) <= 1e-5f) { have = true; break; }   // wave-uniform
                if (sm1 > 0.0f) lo = tau; else hi = tau;
                float tn2 = tau + sm1 / fmaxf(cnt, 1.0f);   // Newton: s' = -n_int
                if (!(tn2 > lo && tn2 < hi)) tn2 = 0.5f * (lo + hi);
                tau = tn2;
            }
            if (!have) {   // bound-exit: re-eval (s,cnt) at final tau
                float z0 = v0 - tau, z1 = v1 - tau, z2 = v2 - tau, z3 = v3 - tau;
                float c0 = fminf(fmaxf(z0, -CAPW), CAPW);
                float c1 = fminf(fmaxf(z1, -CAPW), CAPW);
                float c2 = fminf(fmaxf(z2, -CAPW), CAPW);
                float c3 = fminf(fmaxf(z3, -CAPW), CAPW);
                s   = wsum(c0 + c1 + c2 + c3);
                cnt = wsum((fabsf(z0) < CAPW ? 1.f : 0.f) +
                           (fabsf(z1) < CAPW ? 1.f : 0.f) +
                           (fabsf(z2) < CAPW ? 1.f : 0.f) +
                           (fabsf(z3) < CAPW ? 1.f : 0.f));
                sm1 = s - 1.0f;
            }
            // exact active-set tau == one Newton step from converged point
            float tauf = tau + sm1 / fmaxf(cnt, 1.0f);
            tau_ws = tauf;
            float w0n = fminf(fmaxf(v0 - tauf, -CAPW), CAPW);
            float w1n = fminf(fmaxf(v1 - tauf, -CAPW), CAPW);
            float w2n = fminf(fmaxf(v2 - tauf, -CAPW), CAPW);
            float w3n = fminf(fmaxf(v3 - tauf, -CAPW), CAPW);

            float tn = 0.5f * (1.0f + sqrtf(1.0f + 4.0f * t * t));
            float beta = (t - 1.0f) / tn;
            float y0n = w0n + beta * (w0n - wa);
            float y1n = w1n + beta * (w1n - wb);
            float y2n = w2n + beta * (w2n - wc);
            float y3n = w3n + beta * (w3n - wd);

            float dm = fmaxf(fmaxf(fabsf(w0n - wa), fabsf(w1n - wb)),
                             fmaxf(fabsf(w2n - wc), fabsf(w3n - wd)));
            rm = fmaxf(rm, dm);
            if ((itn & 7) == 7) {
                float rmax = wmax(rm);
                if (rmax < 1e-10f && tid == 0) done_flag = 1;
                rm = 0.0f;
            }

            wa = w0n; wb = w1n; wc = w2n; wd = w3n;
            ya = y0n; yb = y1n; yc = y2n; yd = y3n;
            t = tn;
            *(float4*)(y_lds + R0) = make_float4(ya, yb, yc, yd);
        }
    }

    if (tid < 64) {
        *(float4*)(out + b * 256 + R0) = make_float4(wa, wb, wc, wd);
    }
}

extern "C" void kernel_launch(void* const* d_in, const int* in_sizes, int n_in,
                              void* d_out, int out_size, void* d_ws, size_t ws_size,
                              hipStream_t stream) {
    (void)in_sizes; (void)n_in; (void)d_ws; (void)ws_size; (void)out_size;
    const float* A = (const float*)d_in[0];
    float* out = (float*)d_out;
    hipLaunchKernelGGL(markowitz_fista, dim3(512), dim3(512), 0, stream, A, out);
}